// Round 4
// baseline (2067.562 us; speedup 1.0000x reference)
//
#include <hip/hip_runtime.h>

#define NT 1024
#define NB 256            // 256 blocks x 1024 thr = 262144 = n; 1 block/CU (verified geometry)
#define MAXIT 100
#define RTOL_F 1e-5f
// SELL-64x1, NATURAL row order. entry j of row -> sell[soff[slice] + j*64 + (row & 63)]
//
// GHYSELS-VANROOSE pipelined CG — ONE flag barrier per iteration (see r0 notes).
// r1 lesson: wave-pair row split races — never change dataflow + geometry together.
// r2 lesson: total threads == n pins concurrency at 16 waves/CU; geometry moves hurt.
// r3 lesson: padded gathers were TA-merged (same rq[0] address) => already free;
//            per-lane trip count kept (-8% FETCH) but per-WAVE stage count is
//            governed by slice max J, so the serial chain was untouched.
// THIS ROUND (r4): software-pipeline the SpMV inner chain. Old per-group cost:
//   entry loads -> wait(L_e) -> gathers -> vmcnt(0) (L_g)  == L_e + L_g serial,
//   and the full drain forbids cross-group overlap. New schedule prefetches the
//   NEXT entry group while the CURRENT gather group is in flight; one vmcnt(0)
//   covers both concurrent groups => stall ~= max(L_e, L_g). FMA order is
//   unchanged (j, u ascending) => bit-identical results. All loop VMEM is
//   inline asm so compiler waitcnt bookkeeping stays consistent; "+v" ties
//   order consumers after the wait (proven wait16x8 pattern).
// w moves via 16B uncached (sc0 sc1) ops through the MALL coherence point; no
// cache maintenance in-loop (round-8 lesson: per-iter wbL2/invL2 = +100%).

typedef float f4 __attribute__((ext_vector_type(4)));

__device__ __forceinline__ unsigned long long pk2(float a, float b) {
    return ((unsigned long long)__float_as_uint(b) << 32) | (unsigned long long)__float_as_uint(a);
}

// 16B uncached (coherence-point) load: ISSUE ONLY — result invalid until wait.
__device__ __forceinline__ void ld16_cc(const f4* a, f4& d) {
    asm volatile("global_load_dwordx4 %0, %1, off sc0 sc1" : "=v"(d) : "v"(a));
}
// 8B cached entry load: ISSUE ONLY — result invalid until wait.
__device__ __forceinline__ void ld8e(const long long* a, long long& d) {
    asm volatile("global_load_dwordx2 %0, %1, off" : "=v"(d) : "v"(a));
}
// Drain all VMEM; ties 8 entry regs (prologue wait).
__device__ __forceinline__ void wait_e8(long long& a, long long& b, long long& c, long long& d,
                                        long long& e, long long& f, long long& g, long long& h) {
    asm volatile("s_waitcnt vmcnt(0)"
                 : "+v"(a), "+v"(b), "+v"(c), "+v"(d),
                   "+v"(e), "+v"(f), "+v"(g), "+v"(h));
}
// Drain all VMEM; ties 8 gather regs + 8 (possibly prefetched) entry regs.
__device__ __forceinline__ void wait_g8e8(f4& g0, f4& g1, f4& g2, f4& g3,
                                          f4& g4, f4& g5, f4& g6, f4& g7,
                                          long long& a, long long& b, long long& c, long long& d,
                                          long long& e, long long& f, long long& g, long long& h) {
    asm volatile("s_waitcnt vmcnt(0)"
                 : "+v"(g0), "+v"(g1), "+v"(g2), "+v"(g3),
                   "+v"(g4), "+v"(g5), "+v"(g6), "+v"(g7),
                   "+v"(a), "+v"(b), "+v"(c), "+v"(d),
                   "+v"(e), "+v"(f), "+v"(g), "+v"(h));
}
// 16B uncached (coherence-point) store.
__device__ __forceinline__ void st16_cc(f4* a, f4 v) {
    asm volatile("global_store_dwordx4 %0, %1, off sc0 sc1" :: "v"(a), "v"(v) : "memory");
}

// ---- distributed flag barrier (relaxed spin; vmcnt drained by __syncthreads) ----
__device__ __forceinline__ void fbar(int* flags, int seq) {
    __syncthreads();
    if (threadIdx.x == 0)
        __hip_atomic_store(&flags[blockIdx.x], seq, __ATOMIC_RELAXED, __HIP_MEMORY_SCOPE_AGENT);
    if (threadIdx.x < 64) {
        const int b4 = threadIdx.x << 2;
        for (;;) {
            const int f0 = __hip_atomic_load(&flags[b4 + 0], __ATOMIC_RELAXED, __HIP_MEMORY_SCOPE_AGENT);
            const int f1 = __hip_atomic_load(&flags[b4 + 1], __ATOMIC_RELAXED, __HIP_MEMORY_SCOPE_AGENT);
            const int f2 = __hip_atomic_load(&flags[b4 + 2], __ATOMIC_RELAXED, __HIP_MEMORY_SCOPE_AGENT);
            const int f3 = __hip_atomic_load(&flags[b4 + 3], __ATOMIC_RELAXED, __HIP_MEMORY_SCOPE_AGENT);
            const bool ok = (f0 >= seq) && (f1 >= seq) && (f2 >= seq) && (f3 >= seq);
            if (__all(ok)) break;
            __builtin_amdgcn_s_sleep(1);
        }
    }
    __syncthreads();
}

// heavy variant for setup phases: full agent cache maintenance around arrival
__device__ __forceinline__ void fbar_heavy(int* flags, int seq) {
    __builtin_amdgcn_fence(__ATOMIC_RELEASE, "agent");
    fbar(flags, seq);
    __builtin_amdgcn_fence(__ATOMIC_ACQUIRE, "agent");
}

// Block-wide sum of two floats, broadcast to all threads (deterministic order).
__device__ __forceinline__ float2 block_sum2_bcast(float a, float b, float* smf) {
#pragma unroll
    for (int o = 32; o > 0; o >>= 1) { a += __shfl_down(a, o); b += __shfl_down(b, o); }
    __syncthreads();
    const int w = threadIdx.x >> 6;
    if ((threadIdx.x & 63) == 0) { smf[w] = a; smf[16 + w] = b; }
    __syncthreads();
    float ra = 0.f, rb = 0.f;
#pragma unroll
    for (int i = 0; i < 16; ++i) { ra += smf[i]; rb += smf[16 + i]; }
    return make_float2(ra, rb);
}

// Sum NB packed (gamma,delta) partials from the given buffer — identical per block.
__device__ __forceinline__ float2 sum_parts2(const unsigned long long* buf, float* smf) {
    float a = 0.f, b = 0.f;
    if (threadIdx.x < NB) {
        unsigned long long u = __hip_atomic_load(&buf[threadIdx.x], __ATOMIC_RELAXED,
                                                 __HIP_MEMORY_SCOPE_AGENT);
        a = __uint_as_float((unsigned)(u & 0xffffffffu));
        b = __uint_as_float((unsigned)(u >> 32));
    }
    return block_sum2_bcast(a, b, smf);
}

// Inclusive scan of one int per thread across the block (NT), via LDS.
__device__ __forceinline__ int block_incl_scan(int v, int* smi) {
    const int t = threadIdx.x;
    smi[t] = v;
    __syncthreads();
    for (int off = 1; off < NT; off <<= 1) {
        int add = (t >= off) ? smi[t - off] : 0;
        __syncthreads();
        v += add;
        smi[t] = v;
        __syncthreads();
    }
    return v;
}

#define LD_E8(buf, p)                                   \
    {                                                   \
        _Pragma("unroll")                               \
        for (int u = 0; u < 8; ++u) ld8e((p) + u * 64, buf[u]); \
    }
#define ISSUE_G8(buf)                                   \
    ld16_cc(rq + (int)(buf[0] & 0xffffffffLL), g0);     \
    ld16_cc(rq + (int)(buf[1] & 0xffffffffLL), g1);     \
    ld16_cc(rq + (int)(buf[2] & 0xffffffffLL), g2);     \
    ld16_cc(rq + (int)(buf[3] & 0xffffffffLL), g3);     \
    ld16_cc(rq + (int)(buf[4] & 0xffffffffLL), g4);     \
    ld16_cc(rq + (int)(buf[5] & 0xffffffffLL), g5);     \
    ld16_cc(rq + (int)(buf[6] & 0xffffffffLL), g6);     \
    ld16_cc(rq + (int)(buf[7] & 0xffffffffLL), g7);
#define FMA8(buf)                                       \
    a4 += __int_as_float((int)(buf[0] >> 32)) * g0;     \
    a4 += __int_as_float((int)(buf[1] >> 32)) * g1;     \
    a4 += __int_as_float((int)(buf[2] >> 32)) * g2;     \
    a4 += __int_as_float((int)(buf[3] >> 32)) * g3;     \
    a4 += __int_as_float((int)(buf[4] >> 32)) * g4;     \
    a4 += __int_as_float((int)(buf[5] >> 32)) * g5;     \
    a4 += __int_as_float((int)(buf[6] >> 32)) * g6;     \
    a4 += __int_as_float((int)(buf[7] >> 32)) * g7;

// One SELL row SpMV, unroll-8, per-lane trip count c (multiple of 8),
// SOFTWARE-PIPELINED: next entry group prefetched under current gather flight.
// FMA order identical to the unpipelined version -> bit-identical results.
__device__ __forceinline__ f4 spmv_row(const long long* __restrict__ bp0, int c,
                                       const f4* __restrict__ rq) {
    f4 a4 = {0.f, 0.f, 0.f, 0.f};
    if (c <= 0) return a4;
    long long ea[8], eb[8];
    f4 g0, g1, g2, g3, g4, g5, g6, g7;
    const long long* p = bp0;

    // prologue: E0 -> wait -> G0 (+ E1 prefetch under G0 flight)
    LD_E8(ea, p);
    wait_e8(ea[0], ea[1], ea[2], ea[3], ea[4], ea[5], ea[6], ea[7]);
    ISSUE_G8(ea);
    int j = 8;
    p += 512;
    if (j < c) LD_E8(eb, p);

    for (;;) {
        // phase A: gathers(ea-addressed) + eb-prefetch in flight concurrently
        wait_g8e8(g0, g1, g2, g3, g4, g5, g6, g7,
                  eb[0], eb[1], eb[2], eb[3], eb[4], eb[5], eb[6], eb[7]);
        FMA8(ea);
        if (j >= c) break;
        ISSUE_G8(eb);
        j += 8;
        p += 512;
        if (j < c) LD_E8(ea, p);

        // phase B: gathers(eb-addressed) + ea-prefetch in flight concurrently
        wait_g8e8(g0, g1, g2, g3, g4, g5, g6, g7,
                  ea[0], ea[1], ea[2], ea[3], ea[4], ea[5], ea[6], ea[7]);
        FMA8(eb);
        if (j >= c) break;
        ISSUE_G8(ea);
        j += 8;
        p += 512;
        if (j < c) LD_E8(eb, p);
    }
    return a4;
}

__global__ void __launch_bounds__(NT, 4)
cg_solver_kernel(const float* __restrict__ values,
                 const f4* __restrict__ bvec,
                 const int* __restrict__ rowi,
                 const int* __restrict__ coli,
                 f4* __restrict__ x,                   // = d_out
                 f4* __restrict__ wA,                  // w buffer (even-k gather source)
                 f4* __restrict__ wB,                  // w buffer (odd-k gather source)
                 int* __restrict__ counts,
                 int* __restrict__ ridx,
                 int* __restrict__ jarr,
                 int* __restrict__ soff,
                 unsigned long long* __restrict__ part, // 2*NB packed partials (dbuf)
                 int* __restrict__ flags,               // NB barrier flags (memset 0)
                 long long* __restrict__ sell,
                 int n, int nnz, int nslice)
{
    const int t = threadIdx.x;
    const int tid = blockIdx.x * NT + t;
    const int nth = gridDim.x * NT;          // == n
    __shared__ int smi[NT];
    __shared__ float smf[32];
    int seq = 0;

    // ---- Phase A: zero counters ----
    for (int i = tid; i < n; i += nth) { counts[i] = 0; ridx[i] = 0; }
    fbar_heavy(flags, ++seq);

    // ---- Phase B: histogram + keep b in registers; publish r0=b into wB ----
    for (int e = tid; e < nnz; e += nth) atomicAdd(&counts[rowi[e]], 1);
    f4 rv = bvec[tid];                       // r_0 = b (register-resident)
    st16_cc(&wB[tid], rv);
    fbar_heavy(flags, ++seq);

    // ---- Phase C: per-slice padded slot count (multiple of 8 for unroll-8) ----
    for (int s = tid; s < nslice; s += nth) {
        const int rb = s << 6;
        int m = 0;
#pragma unroll 4
        for (int i = 0; i < 64; ++i) m = max(m, counts[rb + i]);
        jarr[s] = (m + 7) & ~7;
    }
    fbar_heavy(flags, ++seq);

    // ---- Phase D: block 0 scans slice sizes -> soff ----
    if (blockIdx.x == 0) {
        const int spt = (nslice + NT - 1) / NT;
        const int base = t * spt;
        int local = 0;
        for (int i = 0; i < spt; ++i) {
            int s = base + i;
            if (s < nslice) local += 64 * jarr[s];
        }
        int incl = block_incl_scan(local, smi);
        int run = incl - local;
        for (int i = 0; i < spt; ++i) {
            int s = base + i;
            if (s < nslice) { soff[s] = run; run += 64 * jarr[s]; }
        }
        if (t == NT - 1) soff[nslice] = incl;
    }
    fbar_heavy(flags, ++seq);

    // ---- Phase E: zero-fill SELL ----
    {
        const int total = soff[nslice];
        for (int i = tid; i < total; i += nth) sell[i] = 0LL;
    }
    fbar_heavy(flags, ++seq);

    // ---- Phase F: scatter COO -> SELL ----
    for (int e = tid; e < nnz; e += nth) {
        const int rr = rowi[e];
        const int i = atomicAdd(&ridx[rr], 1);
        const int pos = soff[rr >> 6] + (i << 6) + (rr & 63);
        sell[pos] = ((long long)__float_as_int(values[e]) << 32) | (unsigned int)coli[e];
    }
    fbar_heavy(flags, ++seq);

    // ---- GV state (all owner-local, registers; x written once at end) ----
    const int wid = tid >> 6;
    const int lane = t & 63;
    const long long* __restrict__ bp0 = sell + soff[wid] + lane;
    const int c = (counts[tid] + 7) & ~7;    // PER-LANE trip count (real entries only)

    f4 pv = {0.f, 0.f, 0.f, 0.f};
    f4 sv = {0.f, 0.f, 0.f, 0.f};
    f4 zv = {0.f, 0.f, 0.f, 0.f};
    f4 xv = {0.f, 0.f, 0.f, 0.f};
    f4 wv;

    // ---- init: w0 = A r0 (gather wB); store w0 -> wA (iter-0 source);
    //      publish part[0] = (gamma0 = r.r, delta0 = r.w) ----
    {
        wv = spmv_row(bp0, c, wB);
        st16_cc(&wA[tid], wv);
        float g_p = rv.x * rv.x + rv.y * rv.y + rv.z * rv.z + rv.w * rv.w;
        float d_p = rv.x * wv.x + rv.y * wv.y + rv.z * wv.z + rv.w * wv.w;
        float2 tot = block_sum2_bcast(g_p, d_p, smf);
        if (t == 0)
            __hip_atomic_store(&part[blockIdx.x], pk2(tot.x, tot.y), __ATOMIC_RELAXED, __HIP_MEMORY_SCOPE_AGENT);
    }
    fbar(flags, ++seq);

    float tol2 = 0.f;
    float rho_prev = 1.f;
    float alpha = 1.f;

    for (int k = 0;; ++k) {
        // --- scalars: read iter-k partials (closed since last fbar) ---
        float2 rm = sum_parts2(part + (k & 1) * NB, smf);  // (gamma_k, delta_k)
        if (k == 0) tol2 = RTOL_F * RTOL_F * rm.x;
        if (!(rm.x > tol2 && k < MAXIT)) break;
        const float beta = (k == 0) ? 0.f : rm.x / rho_prev;
        alpha = rm.x / (rm.y - beta * rm.x / alpha);       // beta=0 -> gamma/delta
        rho_prev = rm.x;

        // --- SpMV: q_k = A w_k, gathering wbuf[k&1] (published before last fbar) ---
        const f4* wq = (k & 1) ? wB : wA;
        f4 qv = spmv_row(bp0, c, wq);

        // --- GV register recurrences ---
        zv = qv + beta * zv;       // z = A s
        sv = wv + beta * sv;       // s = A p
        pv = rv + beta * pv;
        xv = xv + alpha * pv;
        rv = rv - alpha * sv;
        wv = wv - alpha * zv;      // w = A r maintained by recurrence

        // --- publish w_{k+1} (other buffer) + iter-(k+1) partials; ONE barrier ---
        f4* wt = (k & 1) ? wA : wB;
        st16_cc(&wt[tid], wv);
        {
            float g_p = rv.x * rv.x + rv.y * rv.y + rv.z * rv.z + rv.w * rv.w;
            float d_p = rv.x * wv.x + rv.y * wv.y + rv.z * wv.z + rv.w * wv.w;
            float2 tot = block_sum2_bcast(g_p, d_p, smf);
            if (t == 0)
                __hip_atomic_store(&part[((k + 1) & 1) * NB + blockIdx.x], pk2(tot.x, tot.y),
                                   __ATOMIC_RELAXED, __HIP_MEMORY_SCOPE_AGENT);
        }
        fbar(flags, ++seq);
    }

    x[tid] = xv;   // single write of the solution
}

extern "C" void kernel_launch(void* const* d_in, const int* in_sizes, int n_in,
                              void* d_out, int out_size, void* d_ws, size_t ws_size,
                              hipStream_t stream) {
    const float* values = (const float*)d_in[0];
    const f4* bvec      = (const f4*)d_in[1];
    const int* rowi     = (const int*)d_in[2];
    const int* coli     = (const int*)d_in[3];
    const int nnz = in_sizes[0];
    const int n   = in_sizes[1] / 4;  // F = 4
    const int nslice = n / 64;

    char* ws = (char*)d_ws;
    size_t off = 0;
    auto alloc = [&](size_t bytes) -> void* {
        off = (off + 255) & ~(size_t)255;
        void* pp = ws + off;
        off += bytes;
        return pp;
    };
    int* flags   = (int*)alloc((size_t)NB * 4);       // barrier flags (memset 0)
    f4* wA       = (f4*)alloc((size_t)n * 16);
    f4* wB       = (f4*)alloc((size_t)n * 16);
    unsigned long long* part = (unsigned long long*)alloc((size_t)2 * NB * 8);
    int* counts  = (int*)alloc((size_t)n * 4);
    int* ridx    = (int*)alloc((size_t)n * 4);
    int* jarr    = (int*)alloc((size_t)nslice * 4);
    int* soff    = (int*)alloc((size_t)(nslice + 1) * 4);
    off = (off + 255) & ~(size_t)255;
    long long* sell = (long long*)(ws + off);         // rest of ws (~65 MB)
    f4* x = (f4*)d_out;

    hipMemsetAsync(flags, 0, (size_t)NB * 4, stream);

    int n_ = n, nnz_ = nnz, nslice_ = nslice;
    void* args[] = {
        (void*)&values, (void*)&bvec, (void*)&rowi, (void*)&coli,
        (void*)&x, (void*)&wA, (void*)&wB,
        (void*)&counts, (void*)&ridx, (void*)&jarr, (void*)&soff,
        (void*)&part, (void*)&flags,
        (void*)&sell, (void*)&n_, (void*)&nnz_, (void*)&nslice_
    };
    hipLaunchCooperativeKernel((void*)cg_solver_kernel, dim3(NB), dim3(NT),
                               args, 0, stream);
}

// Round 5
// 1961.738 us; speedup vs baseline: 1.0539x; 1.0539x over previous
//
#include <hip/hip_runtime.h>

#define NT 1024
#define NB 256            // 256 blocks x 1024 thr = 262144 = n; 1 block/CU (verified geometry)
#define MAXIT 100
#define RTOL_F 1e-5f
// SELL-64x1, NATURAL row order. entry j of row -> sell[soff[slice] + j*64 + (row & 63)]
//
// GHYSELS-VANROOSE pipelined CG — ONE flag barrier per iteration (see r0 notes).
// r1 lesson: wave-pair row split races — never change dataflow + geometry together.
// r2 lesson: total threads == n pins concurrency at 16 waves/CU; geometry moves hurt.
// r3 lesson: padded gathers are TA-merged (same rq[0] address) => free; per-lane
//            trip count kept (-8% FETCH).
// r4 lesson: manual entry-prefetch SWP regressed — the compiler already hides
//            entry latency with fine-grained vmcnt(N); full-drain asm waits and
//            extra buffers only add VGPR + FETCH. Leave entry scheduling to it.
// MODEL (r4 post-mortem): ~38 iters, ~40us/iter => 5.8 cy/gather/CU. Little's
// law: 16 waves/CU x 8 in-flight gathers = 128 outstanding at L~745cy =>
// 0.172 req/cy = 5.8 cy/gather — concurrency-limited, not service-limited.
// THIS ROUND (r5): unroll 8 -> 12. 12 gathers in flight per wave => 192
// outstanding/CU => predicted gather phase 40 -> ~27us/iter. Padding ceil8 ->
// ceil12 everywhere (slice jarr and per-lane c); padded slots (col 0) are
// TA-merged and contribute +0.0 in unchanged ascending FMA order. VGPR ~112
// of the 128 cap (launch_bounds(1024,4)) -> no spill, occupancy unchanged.
// w moves via 16B uncached (sc0 sc1) ops through the MALL coherence point; no
// cache maintenance in-loop (round-8 lesson: per-iter wbL2/invL2 = +100%).

typedef float f4 __attribute__((ext_vector_type(4)));

__device__ __forceinline__ unsigned long long pk2(float a, float b) {
    return ((unsigned long long)__float_as_uint(b) << 32) | (unsigned long long)__float_as_uint(a);
}

// 16B uncached (coherence-point) load: ISSUE ONLY — result invalid until wait.
__device__ __forceinline__ void ld16_cc(const f4* a, f4& d) {
    asm volatile("global_load_dwordx4 %0, %1, off sc0 sc1" : "=v"(d) : "v"(a));
}
// Wait for all VMEM; ties the 12 gather results so uses can't be hoisted above.
__device__ __forceinline__ void wait16x12(f4& a, f4& b, f4& c, f4& d,
                                          f4& e, f4& f, f4& g, f4& h,
                                          f4& i, f4& j, f4& k, f4& l) {
    asm volatile("s_waitcnt vmcnt(0)"
                 : "+v"(a), "+v"(b), "+v"(c), "+v"(d),
                   "+v"(e), "+v"(f), "+v"(g), "+v"(h),
                   "+v"(i), "+v"(j), "+v"(k), "+v"(l));
}
// 16B uncached (coherence-point) store.
__device__ __forceinline__ void st16_cc(f4* a, f4 v) {
    asm volatile("global_store_dwordx4 %0, %1, off sc0 sc1" :: "v"(a), "v"(v) : "memory");
}

// ---- distributed flag barrier (relaxed spin; vmcnt drained by __syncthreads) ----
__device__ __forceinline__ void fbar(int* flags, int seq) {
    __syncthreads();
    if (threadIdx.x == 0)
        __hip_atomic_store(&flags[blockIdx.x], seq, __ATOMIC_RELAXED, __HIP_MEMORY_SCOPE_AGENT);
    if (threadIdx.x < 64) {
        const int b4 = threadIdx.x << 2;
        for (;;) {
            const int f0 = __hip_atomic_load(&flags[b4 + 0], __ATOMIC_RELAXED, __HIP_MEMORY_SCOPE_AGENT);
            const int f1 = __hip_atomic_load(&flags[b4 + 1], __ATOMIC_RELAXED, __HIP_MEMORY_SCOPE_AGENT);
            const int f2 = __hip_atomic_load(&flags[b4 + 2], __ATOMIC_RELAXED, __HIP_MEMORY_SCOPE_AGENT);
            const int f3 = __hip_atomic_load(&flags[b4 + 3], __ATOMIC_RELAXED, __HIP_MEMORY_SCOPE_AGENT);
            const bool ok = (f0 >= seq) && (f1 >= seq) && (f2 >= seq) && (f3 >= seq);
            if (__all(ok)) break;
            __builtin_amdgcn_s_sleep(1);
        }
    }
    __syncthreads();
}

// heavy variant for setup phases: full agent cache maintenance around arrival
__device__ __forceinline__ void fbar_heavy(int* flags, int seq) {
    __builtin_amdgcn_fence(__ATOMIC_RELEASE, "agent");
    fbar(flags, seq);
    __builtin_amdgcn_fence(__ATOMIC_ACQUIRE, "agent");
}

// Block-wide sum of two floats, broadcast to all threads (deterministic order).
__device__ __forceinline__ float2 block_sum2_bcast(float a, float b, float* smf) {
#pragma unroll
    for (int o = 32; o > 0; o >>= 1) { a += __shfl_down(a, o); b += __shfl_down(b, o); }
    __syncthreads();
    const int w = threadIdx.x >> 6;
    if ((threadIdx.x & 63) == 0) { smf[w] = a; smf[16 + w] = b; }
    __syncthreads();
    float ra = 0.f, rb = 0.f;
#pragma unroll
    for (int i = 0; i < 16; ++i) { ra += smf[i]; rb += smf[16 + i]; }
    return make_float2(ra, rb);
}

// Sum NB packed (gamma,delta) partials from the given buffer — identical per block.
__device__ __forceinline__ float2 sum_parts2(const unsigned long long* buf, float* smf) {
    float a = 0.f, b = 0.f;
    if (threadIdx.x < NB) {
        unsigned long long u = __hip_atomic_load(&buf[threadIdx.x], __ATOMIC_RELAXED,
                                                 __HIP_MEMORY_SCOPE_AGENT);
        a = __uint_as_float((unsigned)(u & 0xffffffffu));
        b = __uint_as_float((unsigned)(u >> 32));
    }
    return block_sum2_bcast(a, b, smf);
}

// Inclusive scan of one int per thread across the block (NT), via LDS.
__device__ __forceinline__ int block_incl_scan(int v, int* smi) {
    const int t = threadIdx.x;
    smi[t] = v;
    __syncthreads();
    for (int off = 1; off < NT; off <<= 1) {
        int add = (t >= off) ? smi[t - off] : 0;
        __syncthreads();
        v += add;
        smi[t] = v;
        __syncthreads();
    }
    return v;
}

// One SELL row SpMV, unroll-12, per-lane trip count c (multiple of 12).
// 12 gathers in flight per wave (was 8) — the concurrency lever. Entry loads
// are plain C loads: the compiler schedules their waits fine-grained (r4
// lesson). FMA order ascending (j, u) — numerically identical modulo the
// free +0.0 of TA-merged padded slots.
__device__ __forceinline__ f4 spmv_row(const long long* __restrict__ bp0, int c,
                                       const f4* __restrict__ rq) {
    f4 a4 = {0.f, 0.f, 0.f, 0.f};
    for (int j = 0; j < c; j += 12) {
        long long e[12];
#pragma unroll
        for (int u = 0; u < 12; ++u) e[u] = bp0[(j + u) * 64];
        f4 g0, g1, g2, g3, g4, g5, g6, g7, g8, g9, g10, g11;
        ld16_cc(rq + (int)(e[0]  & 0xffffffffLL), g0);
        ld16_cc(rq + (int)(e[1]  & 0xffffffffLL), g1);
        ld16_cc(rq + (int)(e[2]  & 0xffffffffLL), g2);
        ld16_cc(rq + (int)(e[3]  & 0xffffffffLL), g3);
        ld16_cc(rq + (int)(e[4]  & 0xffffffffLL), g4);
        ld16_cc(rq + (int)(e[5]  & 0xffffffffLL), g5);
        ld16_cc(rq + (int)(e[6]  & 0xffffffffLL), g6);
        ld16_cc(rq + (int)(e[7]  & 0xffffffffLL), g7);
        ld16_cc(rq + (int)(e[8]  & 0xffffffffLL), g8);
        ld16_cc(rq + (int)(e[9]  & 0xffffffffLL), g9);
        ld16_cc(rq + (int)(e[10] & 0xffffffffLL), g10);
        ld16_cc(rq + (int)(e[11] & 0xffffffffLL), g11);
        wait16x12(g0, g1, g2, g3, g4, g5, g6, g7, g8, g9, g10, g11);
        a4 += __int_as_float((int)(e[0]  >> 32)) * g0;
        a4 += __int_as_float((int)(e[1]  >> 32)) * g1;
        a4 += __int_as_float((int)(e[2]  >> 32)) * g2;
        a4 += __int_as_float((int)(e[3]  >> 32)) * g3;
        a4 += __int_as_float((int)(e[4]  >> 32)) * g4;
        a4 += __int_as_float((int)(e[5]  >> 32)) * g5;
        a4 += __int_as_float((int)(e[6]  >> 32)) * g6;
        a4 += __int_as_float((int)(e[7]  >> 32)) * g7;
        a4 += __int_as_float((int)(e[8]  >> 32)) * g8;
        a4 += __int_as_float((int)(e[9]  >> 32)) * g9;
        a4 += __int_as_float((int)(e[10] >> 32)) * g10;
        a4 += __int_as_float((int)(e[11] >> 32)) * g11;
    }
    return a4;
}

__global__ void __launch_bounds__(NT, 4)
cg_solver_kernel(const float* __restrict__ values,
                 const f4* __restrict__ bvec,
                 const int* __restrict__ rowi,
                 const int* __restrict__ coli,
                 f4* __restrict__ x,                   // = d_out
                 f4* __restrict__ wA,                  // w buffer (even-k gather source)
                 f4* __restrict__ wB,                  // w buffer (odd-k gather source)
                 int* __restrict__ counts,
                 int* __restrict__ ridx,
                 int* __restrict__ jarr,
                 int* __restrict__ soff,
                 unsigned long long* __restrict__ part, // 2*NB packed partials (dbuf)
                 int* __restrict__ flags,               // NB barrier flags (memset 0)
                 long long* __restrict__ sell,
                 int n, int nnz, int nslice)
{
    const int t = threadIdx.x;
    const int tid = blockIdx.x * NT + t;
    const int nth = gridDim.x * NT;          // == n
    __shared__ int smi[NT];
    __shared__ float smf[32];
    int seq = 0;

    // ---- Phase A: zero counters ----
    for (int i = tid; i < n; i += nth) { counts[i] = 0; ridx[i] = 0; }
    fbar_heavy(flags, ++seq);

    // ---- Phase B: histogram + keep b in registers; publish r0=b into wB ----
    for (int e = tid; e < nnz; e += nth) atomicAdd(&counts[rowi[e]], 1);
    f4 rv = bvec[tid];                       // r_0 = b (register-resident)
    st16_cc(&wB[tid], rv);
    fbar_heavy(flags, ++seq);

    // ---- Phase C: per-slice padded slot count (multiple of 12 for unroll-12) ----
    for (int s = tid; s < nslice; s += nth) {
        const int rb = s << 6;
        int m = 0;
#pragma unroll 4
        for (int i = 0; i < 64; ++i) m = max(m, counts[rb + i]);
        jarr[s] = ((m + 11) / 12) * 12;
    }
    fbar_heavy(flags, ++seq);

    // ---- Phase D: block 0 scans slice sizes -> soff ----
    if (blockIdx.x == 0) {
        const int spt = (nslice + NT - 1) / NT;
        const int base = t * spt;
        int local = 0;
        for (int i = 0; i < spt; ++i) {
            int s = base + i;
            if (s < nslice) local += 64 * jarr[s];
        }
        int incl = block_incl_scan(local, smi);
        int run = incl - local;
        for (int i = 0; i < spt; ++i) {
            int s = base + i;
            if (s < nslice) { soff[s] = run; run += 64 * jarr[s]; }
        }
        if (t == NT - 1) soff[nslice] = incl;
    }
    fbar_heavy(flags, ++seq);

    // ---- Phase E: zero-fill SELL ----
    {
        const int total = soff[nslice];
        for (int i = tid; i < total; i += nth) sell[i] = 0LL;
    }
    fbar_heavy(flags, ++seq);

    // ---- Phase F: scatter COO -> SELL ----
    for (int e = tid; e < nnz; e += nth) {
        const int rr = rowi[e];
        const int i = atomicAdd(&ridx[rr], 1);
        const int pos = soff[rr >> 6] + (i << 6) + (rr & 63);
        sell[pos] = ((long long)__float_as_int(values[e]) << 32) | (unsigned int)coli[e];
    }
    fbar_heavy(flags, ++seq);

    // ---- GV state (all owner-local, registers; x written once at end) ----
    const int wid = tid >> 6;
    const int lane = t & 63;
    const long long* __restrict__ bp0 = sell + soff[wid] + lane;
    const int c = ((counts[tid] + 11) / 12) * 12;  // per-lane trip count, multiple of 12

    f4 pv = {0.f, 0.f, 0.f, 0.f};
    f4 sv = {0.f, 0.f, 0.f, 0.f};
    f4 zv = {0.f, 0.f, 0.f, 0.f};
    f4 xv = {0.f, 0.f, 0.f, 0.f};
    f4 wv;

    // ---- init: w0 = A r0 (gather wB); store w0 -> wA (iter-0 source);
    //      publish part[0] = (gamma0 = r.r, delta0 = r.w) ----
    {
        wv = spmv_row(bp0, c, wB);
        st16_cc(&wA[tid], wv);
        float g_p = rv.x * rv.x + rv.y * rv.y + rv.z * rv.z + rv.w * rv.w;
        float d_p = rv.x * wv.x + rv.y * wv.y + rv.z * wv.z + rv.w * wv.w;
        float2 tot = block_sum2_bcast(g_p, d_p, smf);
        if (t == 0)
            __hip_atomic_store(&part[blockIdx.x], pk2(tot.x, tot.y), __ATOMIC_RELAXED, __HIP_MEMORY_SCOPE_AGENT);
    }
    fbar(flags, ++seq);

    float tol2 = 0.f;
    float rho_prev = 1.f;
    float alpha = 1.f;

    for (int k = 0;; ++k) {
        // --- scalars: read iter-k partials (closed since last fbar) ---
        float2 rm = sum_parts2(part + (k & 1) * NB, smf);  // (gamma_k, delta_k)
        if (k == 0) tol2 = RTOL_F * RTOL_F * rm.x;
        if (!(rm.x > tol2 && k < MAXIT)) break;
        const float beta = (k == 0) ? 0.f : rm.x / rho_prev;
        alpha = rm.x / (rm.y - beta * rm.x / alpha);       // beta=0 -> gamma/delta
        rho_prev = rm.x;

        // --- SpMV: q_k = A w_k, gathering wbuf[k&1] (published before last fbar) ---
        const f4* wq = (k & 1) ? wB : wA;
        f4 qv = spmv_row(bp0, c, wq);

        // --- GV register recurrences ---
        zv = qv + beta * zv;       // z = A s
        sv = wv + beta * sv;       // s = A p
        pv = rv + beta * pv;
        xv = xv + alpha * pv;
        rv = rv - alpha * sv;
        wv = wv - alpha * zv;      // w = A r maintained by recurrence

        // --- publish w_{k+1} (other buffer) + iter-(k+1) partials; ONE barrier ---
        f4* wt = (k & 1) ? wA : wB;
        st16_cc(&wt[tid], wv);
        {
            float g_p = rv.x * rv.x + rv.y * rv.y + rv.z * rv.z + rv.w * rv.w;
            float d_p = rv.x * wv.x + rv.y * wv.y + rv.z * wv.z + rv.w * wv.w;
            float2 tot = block_sum2_bcast(g_p, d_p, smf);
            if (t == 0)
                __hip_atomic_store(&part[((k + 1) & 1) * NB + blockIdx.x], pk2(tot.x, tot.y),
                                   __ATOMIC_RELAXED, __HIP_MEMORY_SCOPE_AGENT);
        }
        fbar(flags, ++seq);
    }

    x[tid] = xv;   // single write of the solution
}

extern "C" void kernel_launch(void* const* d_in, const int* in_sizes, int n_in,
                              void* d_out, int out_size, void* d_ws, size_t ws_size,
                              hipStream_t stream) {
    const float* values = (const float*)d_in[0];
    const f4* bvec      = (const f4*)d_in[1];
    const int* rowi     = (const int*)d_in[2];
    const int* coli     = (const int*)d_in[3];
    const int nnz = in_sizes[0];
    const int n   = in_sizes[1] / 4;  // F = 4
    const int nslice = n / 64;

    char* ws = (char*)d_ws;
    size_t off = 0;
    auto alloc = [&](size_t bytes) -> void* {
        off = (off + 255) & ~(size_t)255;
        void* pp = ws + off;
        off += bytes;
        return pp;
    };
    int* flags   = (int*)alloc((size_t)NB * 4);       // barrier flags (memset 0)
    f4* wA       = (f4*)alloc((size_t)n * 16);
    f4* wB       = (f4*)alloc((size_t)n * 16);
    unsigned long long* part = (unsigned long long*)alloc((size_t)2 * NB * 8);
    int* counts  = (int*)alloc((size_t)n * 4);
    int* ridx    = (int*)alloc((size_t)n * 4);
    int* jarr    = (int*)alloc((size_t)nslice * 4);
    int* soff    = (int*)alloc((size_t)(nslice + 1) * 4);
    off = (off + 255) & ~(size_t)255;
    long long* sell = (long long*)(ws + off);         // rest of ws (~75 MB with ceil12 padding)
    f4* x = (f4*)d_out;

    hipMemsetAsync(flags, 0, (size_t)NB * 4, stream);

    int n_ = n, nnz_ = nnz, nslice_ = nslice;
    void* args[] = {
        (void*)&values, (void*)&bvec, (void*)&rowi, (void*)&coli,
        (void*)&x, (void*)&wA, (void*)&wB,
        (void*)&counts, (void*)&ridx, (void*)&jarr, (void*)&soff,
        (void*)&part, (void*)&flags,
        (void*)&sell, (void*)&n_, (void*)&nnz_, (void*)&nslice_
    };
    hipLaunchCooperativeKernel((void*)cg_solver_kernel, dim3(NB), dim3(NT),
                               args, 0, stream);
}

// Round 6
// 1561.462 us; speedup vs baseline: 1.3241x; 1.2563x over previous
//
#include <hip/hip_runtime.h>

#define NT 1024
#define NB 256            // 256 blocks x 1024 thr = 262144 = n; 1 block/CU (verified geometry)
#define MAXIT 100
#define RTOL_F 1e-5f
// SELL-64x1, NATURAL row order. entry j of row -> sell[soff[slice] + j*64 + (row & 63)]
//
// JACOBI-PRECONDITIONED GHYSELS-VANROOSE pipelined CG — ONE barrier/iter.
// r1 lesson: wave-pair row split races — never change dataflow + geometry together.
// r2 lesson: total threads == n pins concurrency at 16 waves/CU; geometry is a no-op.
// r3 lesson: padded gathers are TA-merged (free); per-lane trip count kept.
// r4 lesson: manual SWP regressed — compiler already schedules entry waits well.
// r5 lesson: unroll-12 regressed (compiler re-loads entries at 64 VGPR; FETCH +18%);
//            8 gather-instr = 512 random lane-requests/wave already saturates the
//            per-CU request queue => throughput = Q/L_MALL ~ 5.8 cy/gather, pinned.
// THIS ROUND (r6): cut the ITERATION COUNT. Jacobi PCG (GV Alg. 4): publish
// m = D^{-1} w instead of w; u,q,m are register recurrences; per-iter cost is
// +3 f4 FMAs and a 3rd reduced scalar (rr for the TRUE-residual stop test,
// same semantics as reference). kappa(D^-1/2 A D^-1/2) ~ 15 vs ~22 => ~-20%
// iterations. Diagonal via atomicAdd over col==row entries (self-loops add -w
// to the diagonal legally). SpMV/SELL/barriers byte-identical to r3.
// w moves via 16B uncached (sc0 sc1) ops through the MALL coherence point; no
// cache maintenance in-loop (prior-session lesson: per-iter wbL2/invL2 = +100%).

typedef float f4 __attribute__((ext_vector_type(4)));

__device__ __forceinline__ unsigned long long pk2(float a, float b) {
    return ((unsigned long long)__float_as_uint(b) << 32) | (unsigned long long)__float_as_uint(a);
}
__device__ __forceinline__ float dot4(f4 a, f4 b) {
    return a.x * b.x + a.y * b.y + a.z * b.z + a.w * b.w;
}

// 16B uncached (coherence-point) load: ISSUE ONLY — result invalid until wait.
__device__ __forceinline__ void ld16_cc(const f4* a, f4& d) {
    asm volatile("global_load_dwordx4 %0, %1, off sc0 sc1" : "=v"(d) : "v"(a));
}
// Wait for all VMEM; ties the 8 gather results so uses can't be hoisted above.
__device__ __forceinline__ void wait16x8(f4& a, f4& b, f4& c, f4& d,
                                         f4& e, f4& f, f4& g, f4& h) {
    asm volatile("s_waitcnt vmcnt(0)"
                 : "+v"(a), "+v"(b), "+v"(c), "+v"(d),
                   "+v"(e), "+v"(f), "+v"(g), "+v"(h));
}
// 16B uncached (coherence-point) store.
__device__ __forceinline__ void st16_cc(f4* a, f4 v) {
    asm volatile("global_store_dwordx4 %0, %1, off sc0 sc1" :: "v"(a), "v"(v) : "memory");
}

// ---- distributed flag barrier (relaxed spin; vmcnt drained by __syncthreads) ----
__device__ __forceinline__ void fbar(int* flags, int seq) {
    __syncthreads();
    if (threadIdx.x == 0)
        __hip_atomic_store(&flags[blockIdx.x], seq, __ATOMIC_RELAXED, __HIP_MEMORY_SCOPE_AGENT);
    if (threadIdx.x < 64) {
        const int b4 = threadIdx.x << 2;
        for (;;) {
            const int f0 = __hip_atomic_load(&flags[b4 + 0], __ATOMIC_RELAXED, __HIP_MEMORY_SCOPE_AGENT);
            const int f1 = __hip_atomic_load(&flags[b4 + 1], __ATOMIC_RELAXED, __HIP_MEMORY_SCOPE_AGENT);
            const int f2 = __hip_atomic_load(&flags[b4 + 2], __ATOMIC_RELAXED, __HIP_MEMORY_SCOPE_AGENT);
            const int f3 = __hip_atomic_load(&flags[b4 + 3], __ATOMIC_RELAXED, __HIP_MEMORY_SCOPE_AGENT);
            const bool ok = (f0 >= seq) && (f1 >= seq) && (f2 >= seq) && (f3 >= seq);
            if (__all(ok)) break;
            __builtin_amdgcn_s_sleep(1);
        }
    }
    __syncthreads();
}

// heavy variant for setup phases: full agent cache maintenance around arrival
__device__ __forceinline__ void fbar_heavy(int* flags, int seq) {
    __builtin_amdgcn_fence(__ATOMIC_RELEASE, "agent");
    fbar(flags, seq);
    __builtin_amdgcn_fence(__ATOMIC_ACQUIRE, "agent");
}

// Block-wide sum of three floats, broadcast to all threads (deterministic order).
__device__ __forceinline__ float3 block_sum3_bcast(float a, float b, float c, float* smf) {
#pragma unroll
    for (int o = 32; o > 0; o >>= 1) {
        a += __shfl_down(a, o); b += __shfl_down(b, o); c += __shfl_down(c, o);
    }
    __syncthreads();
    const int w = threadIdx.x >> 6;
    if ((threadIdx.x & 63) == 0) { smf[w] = a; smf[16 + w] = b; smf[32 + w] = c; }
    __syncthreads();
    float ra = 0.f, rb = 0.f, rc = 0.f;
#pragma unroll
    for (int i = 0; i < 16; ++i) { ra += smf[i]; rb += smf[16 + i]; rc += smf[32 + i]; }
    return make_float3(ra, rb, rc);
}

// Sum NB packed partial pairs {(gamma,delta),(rr,_)} from the given dbuf half.
__device__ __forceinline__ float3 sum_parts3(const unsigned long long* buf, float* smf) {
    float a = 0.f, b = 0.f, c = 0.f;
    if (threadIdx.x < NB) {
        unsigned long long u1 = __hip_atomic_load(&buf[threadIdx.x], __ATOMIC_RELAXED,
                                                  __HIP_MEMORY_SCOPE_AGENT);
        unsigned long long u2 = __hip_atomic_load(&buf[NB + threadIdx.x], __ATOMIC_RELAXED,
                                                  __HIP_MEMORY_SCOPE_AGENT);
        a = __uint_as_float((unsigned)(u1 & 0xffffffffu));
        b = __uint_as_float((unsigned)(u1 >> 32));
        c = __uint_as_float((unsigned)(u2 & 0xffffffffu));
    }
    return block_sum3_bcast(a, b, c, smf);
}

// Inclusive scan of one int per thread across the block (NT), via LDS.
__device__ __forceinline__ int block_incl_scan(int v, int* smi) {
    const int t = threadIdx.x;
    smi[t] = v;
    __syncthreads();
    for (int off = 1; off < NT; off <<= 1) {
        int add = (t >= off) ? smi[t - off] : 0;
        __syncthreads();
        v += add;
        smi[t] = v;
        __syncthreads();
    }
    return v;
}

// One SELL row SpMV, unroll-8, per-lane trip count c (multiple of 8) — r3-proven.
__device__ __forceinline__ f4 spmv_row(const long long* __restrict__ bp0, int c,
                                       const f4* __restrict__ rq) {
    f4 a4 = {0.f, 0.f, 0.f, 0.f};
    for (int j = 0; j < c; j += 8) {
        long long e[8];
#pragma unroll
        for (int u = 0; u < 8; ++u) e[u] = bp0[(j + u) * 64];
        f4 g0, g1, g2, g3, g4, g5, g6, g7;
        ld16_cc(rq + (int)(e[0] & 0xffffffffLL), g0);
        ld16_cc(rq + (int)(e[1] & 0xffffffffLL), g1);
        ld16_cc(rq + (int)(e[2] & 0xffffffffLL), g2);
        ld16_cc(rq + (int)(e[3] & 0xffffffffLL), g3);
        ld16_cc(rq + (int)(e[4] & 0xffffffffLL), g4);
        ld16_cc(rq + (int)(e[5] & 0xffffffffLL), g5);
        ld16_cc(rq + (int)(e[6] & 0xffffffffLL), g6);
        ld16_cc(rq + (int)(e[7] & 0xffffffffLL), g7);
        wait16x8(g0, g1, g2, g3, g4, g5, g6, g7);
        a4 += __int_as_float((int)(e[0] >> 32)) * g0;
        a4 += __int_as_float((int)(e[1] >> 32)) * g1;
        a4 += __int_as_float((int)(e[2] >> 32)) * g2;
        a4 += __int_as_float((int)(e[3] >> 32)) * g3;
        a4 += __int_as_float((int)(e[4] >> 32)) * g4;
        a4 += __int_as_float((int)(e[5] >> 32)) * g5;
        a4 += __int_as_float((int)(e[6] >> 32)) * g6;
        a4 += __int_as_float((int)(e[7] >> 32)) * g7;
    }
    return a4;
}

__global__ void __launch_bounds__(NT, 4)
cg_solver_kernel(const float* __restrict__ values,
                 const f4* __restrict__ bvec,
                 const int* __restrict__ rowi,
                 const int* __restrict__ coli,
                 f4* __restrict__ x,                   // = d_out
                 f4* __restrict__ wA,                  // m buffer (even-k gather source)
                 f4* __restrict__ wB,                  // m buffer (odd-k gather source)
                 int* __restrict__ counts,
                 int* __restrict__ ridx,
                 int* __restrict__ jarr,
                 int* __restrict__ soff,
                 unsigned long long* __restrict__ part, // 2 x 2NB packed partials (dbuf)
                 int* __restrict__ flags,               // NB barrier flags (memset 0)
                 float* __restrict__ diag,              // A's diagonal (Jacobi M)
                 long long* __restrict__ sell,
                 int n, int nnz, int nslice)
{
    const int t = threadIdx.x;
    const int tid = blockIdx.x * NT + t;
    const int nth = gridDim.x * NT;          // == n
    __shared__ int smi[NT];
    __shared__ float smf[48];
    int seq = 0;

    // ---- Phase A: zero counters + diag ----
    for (int i = tid; i < n; i += nth) { counts[i] = 0; ridx[i] = 0; diag[i] = 0.f; }
    fbar_heavy(flags, ++seq);

    // ---- Phase B: histogram; keep b in registers ----
    for (int e = tid; e < nnz; e += nth) atomicAdd(&counts[rowi[e]], 1);
    f4 rv = bvec[tid];                       // r_0 = b (register-resident)
    fbar_heavy(flags, ++seq);

    // ---- Phase C: per-slice padded slot count (multiple of 8 for unroll-8) ----
    for (int s = tid; s < nslice; s += nth) {
        const int rb = s << 6;
        int m = 0;
#pragma unroll 4
        for (int i = 0; i < 64; ++i) m = max(m, counts[rb + i]);
        jarr[s] = (m + 7) & ~7;
    }
    fbar_heavy(flags, ++seq);

    // ---- Phase D: block 0 scans slice sizes -> soff ----
    if (blockIdx.x == 0) {
        const int spt = (nslice + NT - 1) / NT;
        const int base = t * spt;
        int local = 0;
        for (int i = 0; i < spt; ++i) {
            int s = base + i;
            if (s < nslice) local += 64 * jarr[s];
        }
        int incl = block_incl_scan(local, smi);
        int run = incl - local;
        for (int i = 0; i < spt; ++i) {
            int s = base + i;
            if (s < nslice) { soff[s] = run; run += 64 * jarr[s]; }
        }
        if (t == NT - 1) soff[nslice] = incl;
    }
    fbar_heavy(flags, ++seq);

    // ---- Phase E: zero-fill SELL ----
    {
        const int total = soff[nslice];
        for (int i = tid; i < total; i += nth) sell[i] = 0LL;
    }
    fbar_heavy(flags, ++seq);

    // ---- Phase F: scatter COO -> SELL; accumulate true diagonal (incl self-loops) ----
    for (int e = tid; e < nnz; e += nth) {
        const int rr = rowi[e];
        const int i = atomicAdd(&ridx[rr], 1);
        const int pos = soff[rr >> 6] + (i << 6) + (rr & 63);
        const int cc = coli[e];
        const float vv = values[e];
        sell[pos] = ((long long)__float_as_int(vv) << 32) | (unsigned int)cc;
        if (cc == rr) atomicAdd(&diag[rr], vv);
    }
    fbar_heavy(flags, ++seq);

    // ---- GV-PCG state (all owner-local, registers; x written once at end) ----
    const int wid = tid >> 6;
    const int lane = t & 63;
    const long long* __restrict__ bp0 = sell + soff[wid] + lane;
    const int c = (counts[tid] + 7) & ~7;    // per-lane trip count (real entries only)
    const float invd = 1.0f / diag[tid];     // Jacobi M^{-1} (diag >= 1 by construction)

    f4 pv = {0.f, 0.f, 0.f, 0.f};
    f4 sv = {0.f, 0.f, 0.f, 0.f};
    f4 zv = {0.f, 0.f, 0.f, 0.f};
    f4 qv = {0.f, 0.f, 0.f, 0.f};
    f4 xv = {0.f, 0.f, 0.f, 0.f};
    f4 uv, wv, mv;

    // ---- publish u0 = M^{-1} r0 into wB (init-SpMV gather source) ----
    uv = invd * rv;
    st16_cc(&wB[tid], uv);
    fbar(flags, ++seq);

    // ---- init: w0 = A u0 (gather wB); m0 = M^{-1} w0 -> wA (iter-0 source);
    //      publish part[0] = (gamma0 = r.u, delta0 = w.u, rr0 = r.r) ----
    {
        wv = spmv_row(bp0, c, wB);
        mv = invd * wv;
        st16_cc(&wA[tid], mv);
        float3 tot = block_sum3_bcast(dot4(rv, uv), dot4(wv, uv), dot4(rv, rv), smf);
        if (t == 0) {
            __hip_atomic_store(&part[blockIdx.x], pk2(tot.x, tot.y), __ATOMIC_RELAXED, __HIP_MEMORY_SCOPE_AGENT);
            __hip_atomic_store(&part[NB + blockIdx.x], pk2(tot.z, 0.f), __ATOMIC_RELAXED, __HIP_MEMORY_SCOPE_AGENT);
        }
    }
    fbar(flags, ++seq);

    float tol2 = 0.f;
    float gamma_prev = 1.f;
    float alpha = 1.f;

    for (int k = 0;; ++k) {
        // --- scalars: read iter-k partials (closed since last fbar) ---
        float3 rm = sum_parts3(part + (k & 1) * 2 * NB, smf);  // (gamma_k, delta_k, rr_k)
        if (k == 0) tol2 = RTOL_F * RTOL_F * rm.z;             // rr_0 = ||b||^2
        if (!(rm.z > tol2 && k < MAXIT)) break;                // TRUE-residual stop (ref semantics)
        const float beta = (k == 0) ? 0.f : rm.x / gamma_prev;
        alpha = rm.x / (rm.y - beta * rm.x / alpha);           // beta=0 -> gamma/delta
        gamma_prev = rm.x;

        // --- SpMV: n_k = A m_k, gathering mbuf[k&1] (published before last fbar) ---
        const f4* wq = (k & 1) ? wB : wA;
        f4 nv = spmv_row(bp0, c, wq);

        // --- GV-PCG register recurrences (Alg. 4) ---
        zv = nv + beta * zv;       // z = A q
        qv = mv + beta * qv;       // q = M^{-1} s
        sv = wv + beta * sv;       // s = A p
        pv = uv + beta * pv;       // p
        xv = xv + alpha * pv;
        rv = rv - alpha * sv;
        uv = uv - alpha * qv;      // u = M^{-1} r
        wv = wv - alpha * zv;      // w = A u
        mv = invd * wv;            // m = M^{-1} w  (next SpMV input)

        // --- publish m_{k+1} (other buffer) + iter-(k+1) partials; ONE barrier ---
        f4* wt = (k & 1) ? wA : wB;
        st16_cc(&wt[tid], mv);
        {
            float3 tot = block_sum3_bcast(dot4(rv, uv), dot4(wv, uv), dot4(rv, rv), smf);
            if (t == 0) {
                const int base = ((k + 1) & 1) * 2 * NB;
                __hip_atomic_store(&part[base + blockIdx.x], pk2(tot.x, tot.y),
                                   __ATOMIC_RELAXED, __HIP_MEMORY_SCOPE_AGENT);
                __hip_atomic_store(&part[base + NB + blockIdx.x], pk2(tot.z, 0.f),
                                   __ATOMIC_RELAXED, __HIP_MEMORY_SCOPE_AGENT);
            }
        }
        fbar(flags, ++seq);
    }

    x[tid] = xv;   // single write of the solution
}

extern "C" void kernel_launch(void* const* d_in, const int* in_sizes, int n_in,
                              void* d_out, int out_size, void* d_ws, size_t ws_size,
                              hipStream_t stream) {
    const float* values = (const float*)d_in[0];
    const f4* bvec      = (const f4*)d_in[1];
    const int* rowi     = (const int*)d_in[2];
    const int* coli     = (const int*)d_in[3];
    const int nnz = in_sizes[0];
    const int n   = in_sizes[1] / 4;  // F = 4
    const int nslice = n / 64;

    char* ws = (char*)d_ws;
    size_t off = 0;
    auto alloc = [&](size_t bytes) -> void* {
        off = (off + 255) & ~(size_t)255;
        void* pp = ws + off;
        off += bytes;
        return pp;
    };
    int* flags   = (int*)alloc((size_t)NB * 4);       // barrier flags (memset 0)
    f4* wA       = (f4*)alloc((size_t)n * 16);
    f4* wB       = (f4*)alloc((size_t)n * 16);
    unsigned long long* part = (unsigned long long*)alloc((size_t)4 * NB * 8);
    int* counts  = (int*)alloc((size_t)n * 4);
    int* ridx    = (int*)alloc((size_t)n * 4);
    int* jarr    = (int*)alloc((size_t)nslice * 4);
    int* soff    = (int*)alloc((size_t)(nslice + 1) * 4);
    float* diag  = (float*)alloc((size_t)n * 4);
    off = (off + 255) & ~(size_t)255;
    long long* sell = (long long*)(ws + off);         // rest of ws (~65 MB)
    f4* x = (f4*)d_out;

    hipMemsetAsync(flags, 0, (size_t)NB * 4, stream);

    int n_ = n, nnz_ = nnz, nslice_ = nslice;
    void* args[] = {
        (void*)&values, (void*)&bvec, (void*)&rowi, (void*)&coli,
        (void*)&x, (void*)&wA, (void*)&wB,
        (void*)&counts, (void*)&ridx, (void*)&jarr, (void*)&soff,
        (void*)&part, (void*)&flags, (void*)&diag,
        (void*)&sell, (void*)&n_, (void*)&nnz_, (void*)&nslice_
    };
    hipLaunchCooperativeKernel((void*)cg_solver_kernel, dim3(NB), dim3(NT),
                               args, 0, stream);
}